// Round 6
// baseline (34.774 us; speedup 1.0000x reference)
//
#include <hip/hip_runtime.h>

#define NN 128
#define HH 256
#define WW 256
#define CC 3
#define HWC (HH * WW * CC)
#define ROWF (WW * CC)     // 768 floats per image row
#define LSTR 195           // LDS stride for 192-float rows: bank=(m+3j)%32, lane-consecutive

typedef float vf4 __attribute__((ext_vector_type(4)));

__device__ __forceinline__ int reflect_idx(int v, int size) {
    int period = 2 * size - 2;
    int m = v % period;
    if (m < 0) m += period;
    return size - 1 - abs(size - 1 - m);
}

__global__ __launch_bounds__(256) void augment_kernel(
    const float* __restrict__ images,
    const int*   __restrict__ xflip_w,
    const float* __restrict__ xflip_gate,
    const int*   __restrict__ yflip_w,
    const float* __restrict__ yflip_gate,
    const int*   __restrict__ rot_w,
    const float* __restrict__ rot_gate,
    const float* __restrict__ trans_w,
    const float* __restrict__ trans_gate,
    float* __restrict__ out)
{
    __shared__ __align__(16) int   rowTab[64];     // source row * 768
    __shared__ __align__(16) int   colc[192];      // col*3 + c (expanded)
    __shared__ __align__(16) float tile[32 * LSTR];

    // XCD swizzle: 4096 blocks, 8 XCDs -> each XCD owns 16 whole samples
    const int bid     = blockIdx.x;
    const int logical = (bid & 7) * 512 + (bid >> 3);
    const int n       = logical >> 5;               // 32 tiles per sample (8 rows x 4 cols)
    const int tile_id = logical & 31;
    const int yo0     = (tile_id >> 2) << 5;        // 32-row tiles
    const int xo0     = (tile_id & 3) << 6;         // 64-col tiles

    // ---- per-sample parameters (wave-uniform) ----
    const bool xf = (xflip_gate[n] < 1.0f) && (xflip_w[n] == 1);
    const bool yf = (yflip_gate[n] < 1.0f) && (yflip_w[n] == 1);
    const int  rw = (rot_gate[n] < 1.0f) ? rot_w[n] : 0;
    const bool fx = ((rw == 1) || (rw == 2)) ^ xf;
    const bool fy = ((rw == 2) || (rw == 3)) ^ yf;
    const bool tr = (rw == 1) || (rw == 3);

    float tw0 = trans_w[n]      * 2.0f - 1.0f;
    float tw1 = trans_w[NN + n] * 2.0f - 1.0f;
    if (!(trans_gate[n] < 1.0f)) { tw0 = 0.0f; tw1 = 0.0f; }
    const int tx = (int)rintf(tw0 * (WW * 0.125f));
    const int ty = (int)rintf(tw1 * (HH * 0.125f));

    // ---- index tables (R5 formulas, extended ranges), one sync ----
    // non-tr: out(i,j) = src[rowTab[i]][colc[j]] ; tr: out(i,j) = src[rowTab[j]][colc[i]]
    {
        const int t = threadIdx.x;
        if (t < 192) {
            const int b = (t * 171) >> 9;      // t/3
            const int c = t - 3 * b;
            int v = tr ? reflect_idx(yo0 + b + ty, HH)
                       : reflect_idx(xo0 + b - tx, WW);
            if (fx) v = WW - 1 - v;
            colc[t] = v * 3 + c;
        } else {
            const int a = t - 192;             // 0..63
            int v = tr ? reflect_idx(xo0 + a - tx, WW)
                       : reflect_idx(yo0 + a + ty, HH);
            if (fy) v = HH - 1 - v;
            rowTab[a] = v * ROWF;
        }
    }
    __syncthreads();

    const float* __restrict__ src = images + (size_t)n * HWC;
    const size_t outBase = (size_t)(n * HH + yo0) * ROWF + xo0 * CC; // 768B aligned

    if (!tr) {
        // ---- direct path: 24 register gathers in flight -> 6 nt float4 stores ----
        vf4* __restrict__ out4 = (vf4*)(out + outBase);
        const int4* colc4 = (const int4*)colc;

        int   ib[6], qb[6];
        int4  off[6];
        float vals[24];
        #pragma unroll
        for (int v = 0; v < 6; ++v) {
            const int f = v * 256 + threadIdx.x;   // float4 index in [0,1536)
            ib[v] = (f * 683) >> 15;               // f/48 (row in tile)
            qb[v] = f - ib[v] * 48;
            off[v] = colc4[qb[v]];
        }
        #pragma unroll
        for (int v = 0; v < 6; ++v) {
            const int base = rowTab[ib[v]];
            vals[v * 4 + 0] = src[base + off[v].x];
            vals[v * 4 + 1] = src[base + off[v].y];
            vals[v * 4 + 2] = src[base + off[v].z];
            vals[v * 4 + 3] = src[base + off[v].w];
        }
        #pragma unroll
        for (int v = 0; v < 6; ++v) {
            vf4 o = { vals[v * 4 + 0], vals[v * 4 + 1],
                      vals[v * 4 + 2], vals[v * 4 + 3] };
            __builtin_nontemporal_store(o, &out4[ib[v] * (ROWF / 4) + qb[v]]);
        }
    } else {
        // ---- transposed path: 24 coalesced row-gathers -> LDS -> nt scalar stores ----
        float vals[24];
        #pragma unroll
        for (int v = 0; v < 24; ++v) {
            const int f = threadIdx.x + v * 256;   // < 6144
            const int g = f >> 5;
            const int j = (g * 171) >> 9;          // f/96: source-row group = out col, 0..63
            const int m = f - 96 * j;              // (i,c) within column
            vals[v] = src[rowTab[j] + colc[m]];
        }
        #pragma unroll
        for (int v = 0; v < 24; ++v) {
            const int f = threadIdx.x + v * 256;
            const int g = f >> 5;
            const int j = (g * 171) >> 9;
            const int m = f - 96 * j;
            const int i = (m * 171) >> 9;          // m/3
            const int c = m - 3 * i;
            tile[i * LSTR + 3 * j + c] = vals[v];  // bank=(m+3j)%32: lane-consecutive
        }
        __syncthreads();
        #pragma unroll
        for (int v = 0; v < 24; ++v) {
            const int e = threadIdx.x + v * 256;   // < 6144
            const int h = e >> 6;
            const int i = (h * 171) >> 9;          // e/192 (output row in tile)
            const int k = e - 192 * i;
            __builtin_nontemporal_store(tile[i * LSTR + k],
                                        &out[outBase + (size_t)i * ROWF + k]);
        }
    }
}

extern "C" void kernel_launch(void* const* d_in, const int* in_sizes, int n_in,
                              void* d_out, int out_size, void* d_ws, size_t ws_size,
                              hipStream_t stream)
{
    const float* images     = (const float*)d_in[0];
    const int*   xflip_w    = (const int*)  d_in[1];
    const float* xflip_gate = (const float*)d_in[2];
    const int*   yflip_w    = (const int*)  d_in[3];
    const float* yflip_gate = (const float*)d_in[4];
    const int*   rot_w      = (const int*)  d_in[5];
    const float* rot_gate   = (const float*)d_in[6];
    const float* trans_w    = (const float*)d_in[7];   // [2*N] flat
    const float* trans_gate = (const float*)d_in[8];   // [N] flat
    float* outp = (float*)d_out;

    dim3 grid(NN * 32);   // 8x4 tiles of 32x64 pixels per sample
    dim3 block(256);
    augment_kernel<<<grid, block, 0, stream>>>(images, xflip_w, xflip_gate,
                                               yflip_w, yflip_gate, rot_w, rot_gate,
                                               trans_w, trans_gate, outp);
}

// Round 8
// 33.653 us; speedup vs baseline: 1.0333x; 1.0333x over previous
//
#include <hip/hip_runtime.h>

#define NN 128
#define HH 256
#define WW 256
#define CC 3
#define HWC (HH * WW * CC)
#define ROWF (WW * CC)     // 768 floats per image row
#define TY 16              // tile rows
#define TX 32              // tile cols
#define LSTR 99            // LDS stride: banks (3i+3j+c) lane-consecutive -> <=2-way (free)

typedef float vf4 __attribute__((ext_vector_type(4)));

__device__ __forceinline__ int reflect_idx(int v, int size) {
    int period = 2 * size - 2;
    int m = v % period;
    if (m < 0) m += period;
    return size - 1 - abs(size - 1 - m);
}

__global__ __launch_bounds__(256) void augment_kernel(
    const float* __restrict__ images,
    const int*   __restrict__ xflip_w,
    const float* __restrict__ xflip_gate,
    const int*   __restrict__ yflip_w,
    const float* __restrict__ yflip_gate,
    const int*   __restrict__ rot_w,
    const float* __restrict__ rot_gate,
    const float* __restrict__ trans_w,
    const float* __restrict__ trans_gate,
    float* __restrict__ out)
{
    __shared__ __align__(16) int   rowTab[32];      // source row * 768
    __shared__ __align__(16) int   colc[96];        // within-row float offset table
    __shared__ __align__(16) float tile[TY * LSTR]; // 6.3 KB transpose staging

    // Sample-major XCD-local ordering: hardware round-robins bid%8 across XCDs.
    // XCD x owns samples [16x, 16x+16); successive slots walk one sample's 128
    // tiles before moving on -> ~256 resident slots/XCD span ~2 samples
    // -> working set ~3 MB (in + write-allocated out) fits the 4 MB XCD L2.
    const int bid     = blockIdx.x;
    const int xcd     = bid & 7;
    const int slot    = bid >> 3;          // 0..2047
    const int n       = xcd * 16 + (slot >> 7);
    const int tile_id = slot & 127;        // 16 tile-rows x 8 tile-cols
    const int yo0     = (tile_id >> 3) << 4;   // 16-row tiles
    const int xo0     = (tile_id & 7) << 5;    // 32-col tiles

    // ---- per-sample parameters (wave-uniform) ----
    const bool xf = (xflip_gate[n] < 1.0f) && (xflip_w[n] == 1);
    const bool yf = (yflip_gate[n] < 1.0f) && (yflip_w[n] == 1);
    const int  rw = (rot_gate[n] < 1.0f) ? rot_w[n] : 0;
    const bool fx = ((rw == 1) || (rw == 2)) ^ xf;
    const bool fy = ((rw == 2) || (rw == 3)) ^ yf;
    const bool tr = (rw == 1) || (rw == 3);

    float tw0 = trans_w[n]      * 2.0f - 1.0f;
    float tw1 = trans_w[NN + n] * 2.0f - 1.0f;
    if (!(trans_gate[n] < 1.0f)) { tw0 = 0.0f; tw1 = 0.0f; }
    const int tx = (int)rintf(tw0 * (WW * 0.125f));
    const int ty = (int)rintf(tw1 * (HH * 0.125f));

    // ---- index tables (R5/R6 formulas, 16x32 extents), one sync ----
    // non-tr: out(i,j) = src[rowTab[i]][colc[3j+c]]   (i<16, j<32)
    // tr:     out(i,j) = src[rowTab[j]][colc[3i+c]]   (i<16, j<32)
    {
        const int t = threadIdx.x;
        if (t < 96) {
            const int b = (t * 171) >> 9;      // t/3
            const int c = t - 3 * b;
            int v = tr ? reflect_idx(yo0 + b + ty, HH)
                       : reflect_idx(xo0 + b - tx, WW);
            if (fx) v = WW - 1 - v;
            colc[t] = v * 3 + c;
        } else if (t < 128) {
            const int a = t - 96;              // 0..31
            int v = tr ? reflect_idx(xo0 + a - tx, WW)
                       : reflect_idx(yo0 + a + ty, HH);
            if (fy) v = HH - 1 - v;
            rowTab[a] = v * ROWF;
        }
    }
    __syncthreads();

    const float* __restrict__ src = images + (size_t)n * HWC;
    const size_t outBase = (size_t)(n * HH + yo0) * ROWF + xo0 * CC; // 384B aligned

    if (!tr) {
        // ---- direct path: register gathers -> nt float4 stores, no LDS ----
        vf4* __restrict__ out4 = (vf4*)(out + outBase);
        const int4* colc4 = (const int4*)colc;

        #pragma unroll
        for (int v = 0; v < 2; ++v) {
            const int f = v * 256 + threadIdx.x;   // float4 index in [0,384)
            if (f < 384) {
                const int i = (f * 683) >> 14;     // f/24 (row in tile)
                const int q = f - i * 24;
                const int4 off = colc4[q];
                const int  base = rowTab[i];
                vf4 o = { src[base + off.x], src[base + off.y],
                          src[base + off.z], src[base + off.w] };
                __builtin_nontemporal_store(o, &out4[i * (ROWF / 4) + q]);
            }
        }
    } else {
        // ---- transposed path: coalesced row-gathers -> LDS -> nt stores ----
        // source rows = 32 (one per output col j), 48-float segments
        float vals[6];
        #pragma unroll
        for (int v = 0; v < 6; ++v) {
            const int f = threadIdx.x + v * 256;   // < 1536
            const int j = (f * 683) >> 15;         // f/48
            const int m = f - 48 * j;              // 3i+c
            vals[v] = src[rowTab[j] + colc[m]];
        }
        #pragma unroll
        for (int v = 0; v < 6; ++v) {
            const int f = threadIdx.x + v * 256;
            const int j = (f * 683) >> 15;
            const int m = f - 48 * j;
            const int i = (m * 171) >> 9;          // m/3
            const int c = m - 3 * i;
            tile[i * LSTR + 3 * j + c] = vals[v];  // banks (3i+3j+c): <=2-way
        }
        __syncthreads();
        #pragma unroll
        for (int v = 0; v < 6; ++v) {
            const int e = threadIdx.x + v * 256;   // < 1536
            const int i = (e * 683) >> 16;         // e/96 (output row in tile)
            const int k = e - 96 * i;
            __builtin_nontemporal_store(tile[i * LSTR + k],
                                        &out[outBase + (size_t)i * ROWF + k]);
        }
    }
}

extern "C" void kernel_launch(void* const* d_in, const int* in_sizes, int n_in,
                              void* d_out, int out_size, void* d_ws, size_t ws_size,
                              hipStream_t stream)
{
    const float* images     = (const float*)d_in[0];
    const int*   xflip_w    = (const int*)  d_in[1];
    const float* xflip_gate = (const float*)d_in[2];
    const int*   yflip_w    = (const int*)  d_in[3];
    const float* yflip_gate = (const float*)d_in[4];
    const int*   rot_w      = (const int*)  d_in[5];
    const float* rot_gate   = (const float*)d_in[6];
    const float* trans_w    = (const float*)d_in[7];   // [2*N] flat
    const float* trans_gate = (const float*)d_in[8];   // [N] flat
    float* outp = (float*)d_out;

    dim3 grid(NN * 128);   // 16x8 tiles of 16x32 pixels per sample
    dim3 block(256);
    augment_kernel<<<grid, block, 0, stream>>>(images, xflip_w, xflip_gate,
                                               yflip_w, yflip_gate, rot_w, rot_gate,
                                               trans_w, trans_gate, outp);
}